// Round 3
// baseline (1558.729 us; speedup 1.0000x reference)
//
#include <hip/hip_runtime.h>

// Problem constants
#define BATCH 256
#define TT 1024
#define IN_DIM 96
#define NU 256
#define NC 10
#define EPS 0.01f
#define BETA 0.5f
#define GAMMA 0.0f
#define TWOLOG2E 2.8853900817779268f   // 2*log2(e): folded into Wa/Esw/Eb

typedef _Float16 f16x8 __attribute__((ext_vector_type(8)));
typedef _Float16 f16x4 __attribute__((ext_vector_type(4)));
typedef float f32x4 __attribute__((ext_vector_type(4)));

// workspace layout (bytes)
// z slab per (t, bb): [w 8][m 16][q 4][8 halfs] = 8KB, u''-permuted unit axis
#define ZP_BYTES ((size_t)TT * 16 * 16 * 256 * 2)       // 134,217,728
#define WSW_OFF  ZP_BYTES
#define WSW_BYTES ((size_t)16384 * 16)                  // 262,144
#define ESW_OFF  (WSW_OFF + WSW_BYTES)

// Unit permutation u'' (8-wave): orig n = w*32 + i*16 + q*4 + r
//                            <->  u'' = w*32 + q*8  + i*4 + r   (w<8,q<4,i<2,r<4)
// h LDS columns, z slab, and W k-axis use u''; W rows / bias / epilogue use orig n.

// ---------------------------------------------------------------------------
// prep_w v10: Wd = EPS*Dm, Wa = (16*2log2e)*A, swapped-mfma A-operands.
// Flat: [w 8][mat 2][c 8][i 2][lane 64][8 halfs]. Row n = orig output unit;
// k element kk = c*32+(l>>4)*8+j indexes u'' -> fetch orig unit invperm(kk).
__global__ void prep_w(const float* __restrict__ C, const float* __restrict__ B,
                       _Float16* __restrict__ Wsw) {
    int u = blockIdx.x * 256 + threadIdx.x;   // 16384 units
    int l = u & 63;
    int i = (u >> 6) & 1;
    int c = (u >> 7) & 7;
    int mat = (u >> 10) & 1;
    int w = u >> 11;                          // 0..7
    int n = w * 32 + i * 16 + (l & 15);       // output unit (orig)
    int kb = c * 32 + (l >> 4) * 8;
    const float* M = mat ? C : B;             // mat0: Dm from B; mat1: A from C
    float scale = mat ? (16.0f * TWOLOG2E) : EPS;
    f16x8 v;
#pragma unroll
    for (int j = 0; j < 8; j++) {
        int kk = kb + j;                      // u''-coord on contraction axis
        int k = (kk >> 5) * 32 + ((kk >> 2) & 1) * 16
              + ((kk >> 3) & 3) * 4 + (kk & 3);   // invperm -> orig unit
        float m1 = M[k * NU + n];
        float m2 = M[n * NU + k];
        float val = BETA * (m1 - m2) + (1.0f - BETA) * (m1 + m2)
                    - ((k == n) ? GAMMA : 0.0f);
        v[j] = (_Float16)(val * scale);
    }
    ((f16x8*)Wsw)[u] = v;
}

// ---------------------------------------------------------------------------
// prep_e (unchanged layout, 2log2e-scaled): [w 4][c 3][i 4][lane 64][8 halfs]
__global__ void prep_e(const float* __restrict__ Ew, _Float16* __restrict__ Esw) {
    int u = blockIdx.x * 256 + threadIdx.x;   // 3072 units
    int l = u & 63;
    int i = (u >> 6) & 3;
    int wc = u >> 8;
    int c = wc % 3;
    int w = wc / 3;
    int n = w * 64 + i * 16 + (l & 15);
    int kb = c * 32 + (l >> 4) * 8;
    f16x8 v;
#pragma unroll
    for (int j = 0; j < 8; j++)
        v[j] = (_Float16)(Ew[n * IN_DIM + kb + j] * TWOLOG2E);
    ((f16x8*)Esw)[u] = v;
}

// ---------------------------------------------------------------------------
// zproj v10: no LDS, no barriers. Wave wz, lane(m,q) holds D[unit][batch=m]
// for orig units wz*64 + i4*16 + q*4 + r (i4=0..3). In u''-coords these are
// two contiguous 8-half groups under w8 = 2wz+(i4>>1):
//   off(w8) = ((w8*16 + m)*4 + q)*8 + (i4&1)*4 + r  -> two 16B stores/lane,
// each wave covering a contiguous 1KB region (fully coalesced).
__global__ __launch_bounds__(256) void zproj(const float* __restrict__ x,
                                             const float* __restrict__ Eb,
                                             const _Float16* __restrict__ Esw,
                                             _Float16* __restrict__ zp) {
    int tid = threadIdx.x;
    int l = tid & 63, wz = tid >> 6, m = l & 15, q = l >> 4;
    int bb = blockIdx.x & 15, tb = blockIdx.x >> 4;
    int t0 = tb * 16, B0 = bb * 16;

    f16x8 ef[3][4];
    const f16x8* Ep = (const f16x8*)Esw;
#pragma unroll
    for (int c = 0; c < 3; c++)
#pragma unroll
        for (int i = 0; i < 4; i++)
            ef[c][i] = Ep[((wz * 3 + c) * 4 + i) * 64 + l];
    // bias per output unit (orig coords): wz*64 + i*16 + q*4 + r (scaled)
    f32x4 ebv[4];
#pragma unroll
    for (int i = 0; i < 4; i++) {
        float4 b4 = *(const float4*)&Eb[wz * 64 + i * 16 + q * 4];
        f32x4 e4 = {b4.x * TWOLOG2E, b4.y * TWOLOG2E,
                    b4.z * TWOLOG2E, b4.w * TWOLOG2E};
        ebv[i] = e4;
    }

    const float* xbase = x + (size_t)(B0 + m) * TT * IN_DIM + q * 8;

    for (int t = 0; t < 16; t++) {
        f16x8 af[3];
#pragma unroll
        for (int c = 0; c < 3; c++) {
            const float* px = xbase + (size_t)(t0 + t) * IN_DIM + c * 32;
            float4 v0 = *(const float4*)px;
            float4 v1 = *(const float4*)(px + 4);
            f16x8 a;
            a[0] = (_Float16)v0.x; a[1] = (_Float16)v0.y;
            a[2] = (_Float16)v0.z; a[3] = (_Float16)v0.w;
            a[4] = (_Float16)v1.x; a[5] = (_Float16)v1.y;
            a[6] = (_Float16)v1.z; a[7] = (_Float16)v1.w;
            af[c] = a;
        }
        f32x4 acc[4];
#pragma unroll
        for (int i = 0; i < 4; i++) acc[i] = ebv[i];
#pragma unroll
        for (int c = 0; c < 3; c++)
#pragma unroll
            for (int i = 0; i < 4; i++)
                acc[i] = __builtin_amdgcn_mfma_f32_16x16x32_f16(ef[c][i], af[c], acc[i], 0, 0, 0);

        f16x8 o0, o1;
#pragma unroll
        for (int r = 0; r < 4; r++) {
            o0[r]     = (_Float16)acc[0][r];
            o0[4 + r] = (_Float16)acc[1][r];
            o1[r]     = (_Float16)acc[2][r];
            o1[4 + r] = (_Float16)acc[3][r];
        }
        _Float16* slab = zp + (((size_t)(t0 + t) * 16 + bb) * 4096);
        *(f16x8*)(slab + ((size_t)(((2 * wz) * 16 + m) * 4 + q)) * 8)     = o0;
        *(f16x8*)(slab + ((size_t)(((2 * wz + 1) * 16 + m) * 4 + q)) * 8) = o1;
    }
}

// ---------------------------------------------------------------------------
// Recurrence v10: TWO independent batch-block chains per WG, interleaved
// between barriers. Weight frags shared by both chains (zero extra regs).
// Each barrier interval advances both chains one step: chain B's independent
// MFMAs/reads fill chain A's latency bubbles. 8 waves (2/SIMD), v8 unit
// decomposition (wave w owns units w*32..+31). h' write = 1x ds_write_b128
// (u''-contiguous); z load = 16B/lane coalesced; raw s_barrier + lgkmcnt only
// so z global prefetch stays in flight across barriers.

__device__ __forceinline__ f16x8 load_z1(const _Float16* __restrict__ zp,
                                         int ts, int bb, size_t voff) {
    ts = (ts > TT - 1) ? TT - 1 : ts;
    return *(const f16x8*)(zp + ((size_t)ts * 16 + bb) * 4096 + voff);
}

__device__ __forceinline__ void epi_store(const f32x4 faccD[2], const f32x4 faccA[2],
                                          float hm[8], _Float16* __restrict__ hn,
                                          int m, int q, int w) {
    f16x8 o;
#pragma unroll
    for (int i = 0; i < 2; i++) {
#pragma unroll
        for (int r = 0; r < 4; r++) {
            float e = __builtin_amdgcn_exp2f(faccA[i][r]);   // 2^(2log2e*(hA+z))
            float R = __builtin_amdgcn_rcpf(e + 1.0f);
            float s = hm[i * 4 + r] + faccD[i][r];           // incl +EPS/16
            hm[i * 4 + r] = s - (2.0f * EPS * 0.0625f) * R;
            o[i * 4 + r] = (_Float16)hm[i * 4 + r];          // h' = h/16
        }
    }
    *(f16x8*)&hn[m * 264 + w * 32 + q * 8] = o;              // 1x b128, u''
}

__device__ __forceinline__ void stepAB(const _Float16* __restrict__ hbA,
                                       _Float16* __restrict__ hnA,
                                       const _Float16* __restrict__ hbB,
                                       _Float16* __restrict__ hnB,
                                       const f16x8 wd[8][2], const f16x8 wa[8][2],
                                       float hmA[8], float hmB[8],
                                       f16x8 zA, f16x8 zB,
                                       int m, int q, int w) {
    f32x4 fDA[2], fAA[2], fDB[2], fAB[2];
    f32x4 dinit = {EPS * 0.0625f, EPS * 0.0625f, EPS * 0.0625f, EPS * 0.0625f};
#pragma unroll
    for (int i = 0; i < 2; i++) {
        fDA[i] = dinit;  fDB[i] = dinit;       // +EPS/16 folded in
        f32x4 za = {(float)zA[i * 4 + 0], (float)zA[i * 4 + 1],
                    (float)zA[i * 4 + 2], (float)zA[i * 4 + 3]};
        f32x4 zb = {(float)zB[i * 4 + 0], (float)zB[i * 4 + 1],
                    (float)zB[i * 4 + 2], (float)zB[i * 4 + 3]};
        fAA[i] = za;  fAB[i] = zb;             // z (pre-scaled by 2log2e)
    }

#pragma unroll
    for (int c = 0; c < 8; c++) {
        f16x8 afA = *(const f16x8*)&hbA[m * 264 + c * 32 + q * 8];
        f16x8 afB = *(const f16x8*)&hbB[m * 264 + c * 32 + q * 8];
#pragma unroll
        for (int i = 0; i < 2; i++) {
            fDA[i] = __builtin_amdgcn_mfma_f32_16x16x32_f16(wd[c][i], afA, fDA[i], 0, 0, 0);
            fAA[i] = __builtin_amdgcn_mfma_f32_16x16x32_f16(wa[c][i], afA, fAA[i], 0, 0, 0);
            fDB[i] = __builtin_amdgcn_mfma_f32_16x16x32_f16(wd[c][i], afB, fDB[i], 0, 0, 0);
            fAB[i] = __builtin_amdgcn_mfma_f32_16x16x32_f16(wa[c][i], afB, fAB[i], 0, 0, 0);
        }
    }

    epi_store(fDA, fAA, hmA, hnA, m, q, w);
    epi_store(fDB, fAB, hmB, hnB, m, q, w);
}

__global__ __launch_bounds__(512, 2) void recur(const _Float16* __restrict__ Wsw,
                                                const _Float16* __restrict__ zp,
                                                const float* __restrict__ Dw,
                                                const float* __restrict__ Db,
                                                float* __restrict__ out) {
    __shared__ __align__(16) _Float16 hA0[16 * 264];
    __shared__ __align__(16) _Float16 hA1[16 * 264];
    __shared__ __align__(16) _Float16 hB0[16 * 264];
    __shared__ __align__(16) _Float16 hB1[16 * 264];
    __shared__ float Yep[16 * 257];
    int tid = threadIdx.x;
    int l = tid & 63, w = tid >> 6, m = l & 15, q = l >> 4;
    int wg = blockIdx.x;
    int bbA = wg * 2, bbB = wg * 2 + 1;

    // resident weight fragments: 32 f16x8 = 128 regs (AGPR-parked), SHARED
    // by both chains.
    f16x8 wd[8][2], wa[8][2];
    const f16x8* Wp = (const f16x8*)Wsw;
#pragma unroll
    for (int c = 0; c < 8; c++)
#pragma unroll
        for (int i = 0; i < 2; i++) {
            wd[c][i] = Wp[(((w * 2 + 0) * 8 + c) * 2 + i) * 64 + l];
            wa[c][i] = Wp[(((w * 2 + 1) * 8 + c) * 2 + i) * 64 + l];
        }
#pragma unroll
    for (int c = 0; c < 8; c++)
#pragma unroll
        for (int i = 0; i < 2; i++)
            asm volatile("" : "+v"(wd[c][i]), "+v"(wa[c][i]));

    float hmA[8], hmB[8];
#pragma unroll
    for (int e = 0; e < 8; e++) { hmA[e] = 0.0f; hmB[e] = 0.0f; }
    for (int idx = tid; idx < 16 * 264; idx += 512) {
        hA0[idx] = (_Float16)0.0f;
        hB0[idx] = (_Float16)0.0f;
    }

    // z offset within (t, bb) slab [w 8][m 16][q 4][8 halfs]: 16B/lane,
    // wave-contiguous 1KB.
    size_t voff = (size_t)((w * 16 + m) * 4 + q) * 8;
    f16x8 zA0 = load_z1(zp, 0, bbA, voff);
    f16x8 zB0 = load_z1(zp, 0, bbB, voff);
    f16x8 zA1 = load_z1(zp, 1, bbA, voff);
    f16x8 zB1 = load_z1(zp, 1, bbB, voff);
    __syncthreads();

    for (int t = 0; t < TT; t += 2) {
        stepAB(hA0, hA1, hB0, hB1, wd, wa, hmA, hmB, zA0, zB0, m, q, w);
        zA0 = load_z1(zp, t + 2, bbA, voff);
        zB0 = load_z1(zp, t + 2, bbB, voff);
        asm volatile("s_waitcnt lgkmcnt(0)" ::: "memory");   // LDS only
        __builtin_amdgcn_s_barrier();                        // z stays in flight
        __builtin_amdgcn_sched_barrier(0);

        stepAB(hA1, hA0, hB1, hB0, wd, wa, hmA, hmB, zA1, zB1, m, q, w);
        zA1 = load_z1(zp, t + 3, bbA, voff);
        zB1 = load_z1(zp, t + 3, bbB, voff);
        asm volatile("s_waitcnt lgkmcnt(0)" ::: "memory");
        __builtin_amdgcn_s_barrier();
        __builtin_amdgcn_sched_barrier(0);
    }

    // epilogue: out[b][c] = h[b][:] @ Dw[c][:] + Db[c]   (h = 16*hm')
    // lane(m,q,w) holds batch m, orig units w*32 + i*16 + q*4 + r
    __syncthreads();
#pragma unroll
    for (int i = 0; i < 2; i++)
#pragma unroll
        for (int r = 0; r < 4; r++)
            Yep[m * 257 + w * 32 + i * 16 + q * 4 + r] = 16.0f * hmA[i * 4 + r];
    __syncthreads();
    if (tid < 160) {
        int rr = tid / 10, c = tid - rr * 10;
        float s = Db[c];
        for (int k = 0; k < 256; k++) s += Yep[rr * 257 + k] * Dw[c * 256 + k];
        out[(bbA * 16 + rr) * 10 + c] = s;
    }
    __syncthreads();
#pragma unroll
    for (int i = 0; i < 2; i++)
#pragma unroll
        for (int r = 0; r < 4; r++)
            Yep[m * 257 + w * 32 + i * 16 + q * 4 + r] = 16.0f * hmB[i * 4 + r];
    __syncthreads();
    if (tid < 160) {
        int rr = tid / 10, c = tid - rr * 10;
        float s = Db[c];
        for (int k = 0; k < 256; k++) s += Yep[rr * 257 + k] * Dw[c * 256 + k];
        out[(bbB * 16 + rr) * 10 + c] = s;
    }
}

// ---------------------------------------------------------------------------
extern "C" void kernel_launch(void* const* d_in, const int* in_sizes, int n_in,
                              void* d_out, int out_size, void* d_ws, size_t ws_size,
                              hipStream_t stream) {
    const float* x  = (const float*)d_in[0];
    const float* Ew = (const float*)d_in[1];
    const float* Eb = (const float*)d_in[2];
    const float* C  = (const float*)d_in[3];
    const float* B  = (const float*)d_in[4];
    const float* Dw = (const float*)d_in[5];
    const float* Db = (const float*)d_in[6];
    float* out = (float*)d_out;

    char* ws = (char*)d_ws;
    _Float16* zp  = (_Float16*)(ws);
    _Float16* Wsw = (_Float16*)(ws + WSW_OFF);
    _Float16* Esw = (_Float16*)(ws + ESW_OFF);

    hipLaunchKernelGGL(prep_w, dim3(64), dim3(256), 0, stream, C, B, Wsw);
    hipLaunchKernelGGL(prep_e, dim3(12), dim3(256), 0, stream, Ew, Esw);
    hipLaunchKernelGGL(zproj, dim3(1024), dim3(256), 0, stream, x, Eb, Esw, zp);
    hipLaunchKernelGGL(recur, dim3(8), dim3(512), 0, stream, Wsw, zp, Dw, Db, out);
}

// Round 4
// 934.532 us; speedup vs baseline: 1.6679x; 1.6679x over previous
//
#include <hip/hip_runtime.h>

// Problem constants
#define BATCH 256
#define TT 1024
#define IN_DIM 96
#define NU 256
#define NC 10
#define EPS 0.01f
#define BETA 0.5f
#define GAMMA 0.0f
#define TWOLOG2E 2.8853900817779268f   // 2*log2(e): folded into Wa/Esw/Eb

typedef _Float16 f16x8 __attribute__((ext_vector_type(8)));
typedef _Float16 f16x4 __attribute__((ext_vector_type(4)));
typedef float f32x4 __attribute__((ext_vector_type(4)));

// workspace layout (bytes)
// z slab per (t, bb): [w 8][m 16][q 4][8 halfs] = 8KB, u''-permuted unit axis
#define ZP_BYTES ((size_t)TT * 16 * 16 * 256 * 2)       // 134,217,728
#define WSW_OFF  ZP_BYTES
#define WSW_BYTES ((size_t)16384 * 16)                  // 262,144
#define ESW_OFF  (WSW_OFF + WSW_BYTES)

// Unit permutation u'' (8-wave): orig n = w*32 + i*16 + q*4 + r
//                            <->  u'' = w*32 + q*8  + i*4 + r   (w<8,q<4,i<2,r<4)
// h LDS columns, z slab, and W k-axis use u''; W rows / bias / epilogue use orig n.

// ---------------------------------------------------------------------------
// prep_w (v10 layout): Wd = EPS*Dm, Wa = (16*2log2e)*A, swapped-mfma A-operands.
// Flat: [w 8][mat 2][c 8][i 2][lane 64][8 halfs]. Row n = orig output unit;
// k element kk = c*32+(l>>4)*8+j indexes u'' -> fetch orig unit invperm(kk).
__global__ void prep_w(const float* __restrict__ C, const float* __restrict__ B,
                       _Float16* __restrict__ Wsw) {
    int u = blockIdx.x * 256 + threadIdx.x;   // 16384 units
    int l = u & 63;
    int i = (u >> 6) & 1;
    int c = (u >> 7) & 7;
    int mat = (u >> 10) & 1;
    int w = u >> 11;                          // 0..7
    int n = w * 32 + i * 16 + (l & 15);       // output unit (orig)
    int kb = c * 32 + (l >> 4) * 8;
    const float* M = mat ? C : B;             // mat0: Dm from B; mat1: A from C
    float scale = mat ? (16.0f * TWOLOG2E) : EPS;
    f16x8 v;
#pragma unroll
    for (int j = 0; j < 8; j++) {
        int kk = kb + j;                      // u''-coord on contraction axis
        int k = (kk >> 5) * 32 + ((kk >> 2) & 1) * 16
              + ((kk >> 3) & 3) * 4 + (kk & 3);   // invperm -> orig unit
        float m1 = M[k * NU + n];
        float m2 = M[n * NU + k];
        float val = BETA * (m1 - m2) + (1.0f - BETA) * (m1 + m2)
                    - ((k == n) ? GAMMA : 0.0f);
        v[j] = (_Float16)(val * scale);
    }
    ((f16x8*)Wsw)[u] = v;
}

// ---------------------------------------------------------------------------
// prep_e (unchanged layout, 2log2e-scaled): [w 4][c 3][i 4][lane 64][8 halfs]
__global__ void prep_e(const float* __restrict__ Ew, _Float16* __restrict__ Esw) {
    int u = blockIdx.x * 256 + threadIdx.x;   // 3072 units
    int l = u & 63;
    int i = (u >> 6) & 3;
    int wc = u >> 8;
    int c = wc % 3;
    int w = wc / 3;
    int n = w * 64 + i * 16 + (l & 15);
    int kb = c * 32 + (l >> 4) * 8;
    f16x8 v;
#pragma unroll
    for (int j = 0; j < 8; j++)
        v[j] = (_Float16)(Ew[n * IN_DIM + kb + j] * TWOLOG2E);
    ((f16x8*)Esw)[u] = v;
}

// ---------------------------------------------------------------------------
// zproj (v10): no LDS, no barriers. Wave wz, lane(m,q) holds D[unit][batch=m]
// for orig units wz*64 + i4*16 + q*4 + r (i4=0..3). In u''-coords these are
// two contiguous 8-half groups under w8 = 2wz+(i4>>1):
//   off(w8) = ((w8*16 + m)*4 + q)*8 + (i4&1)*4 + r  -> two 16B stores/lane,
// each wave covering a contiguous 1KB region (fully coalesced).
__global__ __launch_bounds__(256) void zproj(const float* __restrict__ x,
                                             const float* __restrict__ Eb,
                                             const _Float16* __restrict__ Esw,
                                             _Float16* __restrict__ zp) {
    int tid = threadIdx.x;
    int l = tid & 63, wz = tid >> 6, m = l & 15, q = l >> 4;
    int bb = blockIdx.x & 15, tb = blockIdx.x >> 4;
    int t0 = tb * 16, B0 = bb * 16;

    f16x8 ef[3][4];
    const f16x8* Ep = (const f16x8*)Esw;
#pragma unroll
    for (int c = 0; c < 3; c++)
#pragma unroll
        for (int i = 0; i < 4; i++)
            ef[c][i] = Ep[((wz * 3 + c) * 4 + i) * 64 + l];
    // bias per output unit (orig coords): wz*64 + i*16 + q*4 + r (scaled)
    f32x4 ebv[4];
#pragma unroll
    for (int i = 0; i < 4; i++) {
        float4 b4 = *(const float4*)&Eb[wz * 64 + i * 16 + q * 4];
        f32x4 e4 = {b4.x * TWOLOG2E, b4.y * TWOLOG2E,
                    b4.z * TWOLOG2E, b4.w * TWOLOG2E};
        ebv[i] = e4;
    }

    const float* xbase = x + (size_t)(B0 + m) * TT * IN_DIM + q * 8;

    for (int t = 0; t < 16; t++) {
        f16x8 af[3];
#pragma unroll
        for (int c = 0; c < 3; c++) {
            const float* px = xbase + (size_t)(t0 + t) * IN_DIM + c * 32;
            float4 v0 = *(const float4*)px;
            float4 v1 = *(const float4*)(px + 4);
            f16x8 a;
            a[0] = (_Float16)v0.x; a[1] = (_Float16)v0.y;
            a[2] = (_Float16)v0.z; a[3] = (_Float16)v0.w;
            a[4] = (_Float16)v1.x; a[5] = (_Float16)v1.y;
            a[6] = (_Float16)v1.z; a[7] = (_Float16)v1.w;
            af[c] = a;
        }
        f32x4 acc[4];
#pragma unroll
        for (int i = 0; i < 4; i++) acc[i] = ebv[i];
#pragma unroll
        for (int c = 0; c < 3; c++)
#pragma unroll
            for (int i = 0; i < 4; i++)
                acc[i] = __builtin_amdgcn_mfma_f32_16x16x32_f16(ef[c][i], af[c], acc[i], 0, 0, 0);

        f16x8 o0, o1;
#pragma unroll
        for (int r = 0; r < 4; r++) {
            o0[r]     = (_Float16)acc[0][r];
            o0[4 + r] = (_Float16)acc[1][r];
            o1[r]     = (_Float16)acc[2][r];
            o1[4 + r] = (_Float16)acc[3][r];
        }
        _Float16* slab = zp + (((size_t)(t0 + t) * 16 + bb) * 4096);
        *(f16x8*)(slab + ((size_t)(((2 * wz) * 16 + m) * 4 + q)) * 8)     = o0;
        *(f16x8*)(slab + ((size_t)(((2 * wz + 1) * 16 + m) * 4 + q)) * 8) = o1;
    }
}

// ---------------------------------------------------------------------------
// Recurrence v11: v10's step machinery (u'' single-b128 h' write, raw
// s_barrier + lgkmcnt-only sync, z prefetch never drained by vmcnt(0)) but
// back at FULL grid parallelism: 16 WGs x 1 chain x 8 waves (2/SIMD).
// z prefetch 4 steps deep (~3 step-times in flight > 900-cyc HBM latency).

__device__ __forceinline__ f16x8 load_z1(const _Float16* __restrict__ zp,
                                         int ts, int bb, size_t voff) {
    ts = (ts > TT - 1) ? TT - 1 : ts;
    return *(const f16x8*)(zp + ((size_t)ts * 16 + bb) * 4096 + voff);
}

// one recurrence step for this WG's chain; NO barrier inside (caller syncs)
__device__ __forceinline__ void step_fn(const _Float16* __restrict__ hb,
                                        _Float16* __restrict__ hn,
                                        const f16x8 wd[8][2], const f16x8 wa[8][2],
                                        float hm[8], f16x8 zs,
                                        int m, int q, int w) {
    f32x4 faccD[2], faccA[2];
    f32x4 dinit = {EPS * 0.0625f, EPS * 0.0625f, EPS * 0.0625f, EPS * 0.0625f};
#pragma unroll
    for (int i = 0; i < 2; i++) {
        faccD[i] = dinit;                      // +EPS/16 folded in
        f32x4 zi = {(float)zs[i * 4 + 0], (float)zs[i * 4 + 1],
                    (float)zs[i * 4 + 2], (float)zs[i * 4 + 3]};
        faccA[i] = zi;                         // z (pre-scaled by 2log2e)
    }

#pragma unroll
    for (int c = 0; c < 8; c++) {
        f16x8 af = *(const f16x8*)&hb[m * 264 + c * 32 + q * 8];
#pragma unroll
        for (int i = 0; i < 2; i++) {
            faccD[i] = __builtin_amdgcn_mfma_f32_16x16x32_f16(wd[c][i], af, faccD[i], 0, 0, 0);
            faccA[i] = __builtin_amdgcn_mfma_f32_16x16x32_f16(wa[c][i], af, faccA[i], 0, 0, 0);
        }
    }

    f16x8 o;
#pragma unroll
    for (int i = 0; i < 2; i++) {
#pragma unroll
        for (int r = 0; r < 4; r++) {
            float e = __builtin_amdgcn_exp2f(faccA[i][r]);   // 2^(2log2e*(hA+z))
            float R = __builtin_amdgcn_rcpf(e + 1.0f);
            float s = hm[i * 4 + r] + faccD[i][r];           // incl +EPS/16
            hm[i * 4 + r] = s - (2.0f * EPS * 0.0625f) * R;
            o[i * 4 + r] = (_Float16)hm[i * 4 + r];          // h' = h/16
        }
    }
    *(f16x8*)&hn[m * 264 + w * 32 + q * 8] = o;              // 1x b128, u''
}

#define STEP_SYNC()                                          \
    asm volatile("s_waitcnt lgkmcnt(0)" ::: "memory");       \
    __builtin_amdgcn_s_barrier();                            \
    __builtin_amdgcn_sched_barrier(0)

__global__ __launch_bounds__(512, 2) void recur(const _Float16* __restrict__ Wsw,
                                                const _Float16* __restrict__ zp,
                                                const float* __restrict__ Dw,
                                                const float* __restrict__ Db,
                                                float* __restrict__ out) {
    __shared__ __align__(16) _Float16 hbuf0[16 * 264];
    __shared__ __align__(16) _Float16 hbuf1[16 * 264];
    __shared__ float Yep[16 * 257];
    int tid = threadIdx.x;
    int l = tid & 63, w = tid >> 6, m = l & 15, q = l >> 4;
    int wg = blockIdx.x;

    // resident weight fragments: 32 f16x8 = 128 regs (AGPR-parked)
    f16x8 wd[8][2], wa[8][2];
    const f16x8* Wp = (const f16x8*)Wsw;
#pragma unroll
    for (int c = 0; c < 8; c++)
#pragma unroll
        for (int i = 0; i < 2; i++) {
            wd[c][i] = Wp[(((w * 2 + 0) * 8 + c) * 2 + i) * 64 + l];
            wa[c][i] = Wp[(((w * 2 + 1) * 8 + c) * 2 + i) * 64 + l];
        }
#pragma unroll
    for (int c = 0; c < 8; c++)
#pragma unroll
        for (int i = 0; i < 2; i++)
            asm volatile("" : "+v"(wd[c][i]), "+v"(wa[c][i]));

    float hm[8];
#pragma unroll
    for (int e = 0; e < 8; e++) hm[e] = 0.0f;
    for (int idx = tid; idx < 16 * 264; idx += 512) hbuf0[idx] = (_Float16)0.0f;

    // z offset within (t, bb) slab [w 8][m 16][q 4][8 halfs]: 16B/lane,
    // wave-contiguous 1KB.
    size_t voff = (size_t)((w * 16 + m) * 4 + q) * 8;
    f16x8 z0 = load_z1(zp, 0, wg, voff);
    f16x8 z1 = load_z1(zp, 1, wg, voff);
    f16x8 z2 = load_z1(zp, 2, wg, voff);
    f16x8 z3 = load_z1(zp, 3, wg, voff);
    __syncthreads();

    for (int t = 0; t < TT; t += 4) {
        step_fn(hbuf0, hbuf1, wd, wa, hm, z0, m, q, w);
        z0 = load_z1(zp, t + 4, wg, voff);
        STEP_SYNC();
        step_fn(hbuf1, hbuf0, wd, wa, hm, z1, m, q, w);
        z1 = load_z1(zp, t + 5, wg, voff);
        STEP_SYNC();
        step_fn(hbuf0, hbuf1, wd, wa, hm, z2, m, q, w);
        z2 = load_z1(zp, t + 6, wg, voff);
        STEP_SYNC();
        step_fn(hbuf1, hbuf0, wd, wa, hm, z3, m, q, w);
        z3 = load_z1(zp, t + 7, wg, voff);
        STEP_SYNC();
    }

    // epilogue: out[b][c] = h[b][:] @ Dw[c][:] + Db[c]   (h = 16*hm')
    // lane(m,q,w) holds batch m, orig units w*32 + i*16 + q*4 + r
#pragma unroll
    for (int i = 0; i < 2; i++)
#pragma unroll
        for (int r = 0; r < 4; r++)
            Yep[m * 257 + w * 32 + i * 16 + q * 4 + r] = 16.0f * hm[i * 4 + r];
    __syncthreads();
    if (tid < 160) {
        int rr = tid / 10, c = tid - rr * 10;
        float s = Db[c];
        for (int k = 0; k < 256; k++) s += Yep[rr * 257 + k] * Dw[c * 256 + k];
        out[(wg * 16 + rr) * 10 + c] = s;
    }
}

// ---------------------------------------------------------------------------
extern "C" void kernel_launch(void* const* d_in, const int* in_sizes, int n_in,
                              void* d_out, int out_size, void* d_ws, size_t ws_size,
                              hipStream_t stream) {
    const float* x  = (const float*)d_in[0];
    const float* Ew = (const float*)d_in[1];
    const float* Eb = (const float*)d_in[2];
    const float* C  = (const float*)d_in[3];
    const float* B  = (const float*)d_in[4];
    const float* Dw = (const float*)d_in[5];
    const float* Db = (const float*)d_in[6];
    float* out = (float*)d_out;

    char* ws = (char*)d_ws;
    _Float16* zp  = (_Float16*)(ws);
    _Float16* Wsw = (_Float16*)(ws + WSW_OFF);
    _Float16* Esw = (_Float16*)(ws + ESW_OFF);

    hipLaunchKernelGGL(prep_w, dim3(64), dim3(256), 0, stream, C, B, Wsw);
    hipLaunchKernelGGL(prep_e, dim3(12), dim3(256), 0, stream, Ew, Esw);
    hipLaunchKernelGGL(zproj, dim3(1024), dim3(256), 0, stream, x, Eb, Esw, zp);
    hipLaunchKernelGGL(recur, dim3(16), dim3(512), 0, stream, Wsw, zp, Dw, Db, out);
}